// Round 7
// baseline (112.258 us; speedup 1.0000x reference)
//
#include <hip/hip_runtime.h>

namespace {
constexpr int T_STEPS = 50;
constexpr int BATCH_N = 131072;
constexpr int HIDDEN  = 100;
}

// One thread per batch element; h outer, t inner (fully unrolled).
// Arithmetic = XLA-contracted f32 semantics:
//   cur1 = fma(x1, w1b, RN(x0*w1a))            k-ascending fma chain
//   mem  = fma(spk, -0.5, fma(0.9f, mem, cur)) <- FUSED recurrence (new)
//   cur2 = ascending-h serial fma; spk*w products exact
// All global accesses are scalar 4-byte INTEGER loads/stores carrying f32
// bit patterns (hedge: R4, the only round proven to write, used int stores).
__global__ __launch_bounds__(256)
void snn_fused_kernel(const unsigned int* __restrict__ x_u,
                      const float* __restrict__ W1,
                      const float* __restrict__ W2,
                      unsigned int* __restrict__ out_u)
{
#pragma clang fp contract(off)
    __shared__ float sW1a[HIDDEN], sW1b[HIDDEN], sW20[HIDDEN], sW21[HIDDEN];

    const int tid = threadIdx.x;
    for (int i = tid; i < HIDDEN; i += 256) {
        sW1a[i] = W1[2 * i];          // W1[h][0]
        sW1b[i] = W1[2 * i + 1];      // W1[h][1]
        sW20[i] = W2[i];              // W2[0][h]
        sW21[i] = W2[HIDDEN + i];     // W2[1][h]
    }
    __syncthreads();

    const int b = blockIdx.x * 256 + tid;

    // x: [T, B, 2] f32, read as scalar uints, reinterpreted.
    float x0[T_STEPS], x1[T_STEPS];
#pragma unroll
    for (int t = 0; t < T_STEPS; ++t) {
        size_t base = ((size_t)t * BATCH_N + b) * 2;
        x0[t] = __uint_as_float(x_u[base]);
        x1[t] = __uint_as_float(x_u[base + 1]);
    }

    float acc0[T_STEPS], acc1[T_STEPS];
#pragma unroll
    for (int t = 0; t < T_STEPS; ++t) { acc0[t] = 0.0f; acc1[t] = 0.0f; }

#pragma unroll 2
    for (int h = 0; h < HIDDEN; ++h) {
        const float w1a = sW1a[h];
        const float w1b = sW1b[h];
        const float w20 = sW20[h];
        const float w21 = sW21[h];
        float m = 0.0f;   // mem1[h]
        float s = 0.0f;   // spk1[h] in {0,1}
#pragma unroll
        for (int t = 0; t < T_STEPS; ++t) {
            float cur = fmaf(x1[t], w1b, x0[t] * w1a);   // k-ascending chain
            // fused recurrence: fma(0.9,m,cur) then exact -spk*0.5 fma
            m = fmaf(s, -0.5f, fmaf(0.9f, m, cur));
            s = (m > 0.5f) ? 1.0f : 0.0f;
            acc0[t] = fmaf(s, w20, acc0[t]);   // exact product -> == add
            acc1[t] = fmaf(s, w21, acc1[t]);
        }
    }

    // Outputs: spk_rec then mem_rec, each [T, B, 2] f32; scalar uint stores.
    const size_t mem_off = (size_t)T_STEPS * BATCH_N * 2;
    float m0 = 0.0f, m1 = 0.0f, s0 = 0.0f, s1 = 0.0f;   // spk2 in {0,1}
#pragma unroll
    for (int t = 0; t < T_STEPS; ++t) {
        m0 = fmaf(s0, -0.5f, fmaf(0.9f, m0, acc0[t]));
        m1 = fmaf(s1, -0.5f, fmaf(0.9f, m1, acc1[t]));
        s0 = (m0 > 0.5f) ? 1.0f : 0.0f;
        s1 = (m1 > 0.5f) ? 1.0f : 0.0f;
        size_t cell = ((size_t)t * BATCH_N + b) * 2;
        out_u[cell]               = __float_as_uint(s0);
        out_u[cell + 1]           = __float_as_uint(s1);
        out_u[mem_off + cell]     = __float_as_uint(m0);
        out_u[mem_off + cell + 1] = __float_as_uint(m1);
    }
}

extern "C" void kernel_launch(void* const* d_in, const int* in_sizes, int n_in,
                              void* d_out, int out_size, void* d_ws, size_t ws_size,
                              hipStream_t stream) {
    // Robust input mapping: x = the unique large buffer; W1 precedes W2 among
    // the rest (holds under both dict order [x,W1,W2] and sorted [W1,W2,x]).
    int big = 0;
    for (int i = 1; i < n_in; ++i) if (in_sizes[i] > in_sizes[big]) big = i;
    const void* ptrs[3] = {nullptr, nullptr, nullptr};  // x, W1, W2
    int k = 1;
    ptrs[0] = d_in[big];
    for (int i = 0; i < n_in; ++i) {
        if (i == big) continue;
        ptrs[k++] = d_in[i];
    }
    const unsigned int* x_u = (const unsigned int*)ptrs[0];
    const float* W1 = (const float*)ptrs[1];
    const float* W2 = (const float*)ptrs[2];
    unsigned int* out_u = (unsigned int*)d_out;
    dim3 grid(BATCH_N / 256), block(256);
    hipLaunchKernelGGL(snn_fused_kernel, grid, block, 0, stream, x_u, W1, W2, out_u);
}